// Round 1
// baseline (25861.838 us; speedup 1.0000x reference)
//
#include <hip/hip_runtime.h>
#include <math.h>

#define NWG 64
#define KD 256
#define UD 64
#define XD 128
#define TH 200

// ws float offsets
#define OFF_V    0
#define OFF_VA   65536
#define OFF_H    131072
#define OFF_G    196608
#define OFF_K0   212992
#define OFF_M    229376
#define OFF_MI   233472
#define OFF_v    237568
#define OFF_ATV  237824
#define OFF_Z    238080
#define OFF_GG   238144
#define OFF_QG   238400
#define OFF_QD   238656
#define OFF_RD   238912
#define OFF_KV   238976
#define OFF_NKT  239040
#define OFF_CV   247232
#define OFF_BAR  247296

__device__ __forceinline__ void gbar(unsigned long long* bar) {
  __syncthreads();
  if (threadIdx.x == 0) {
    unsigned long long old = __hip_atomic_fetch_add(bar, 1ull, __ATOMIC_ACQ_REL, __HIP_MEMORY_SCOPE_AGENT);
    unsigned g = (unsigned)(old >> 32);
    if ((unsigned)(old & 0xffffffffull) == (unsigned)(NWG - 1)) {
      __hip_atomic_store(bar, ((unsigned long long)(g + 1u)) << 32, __ATOMIC_RELEASE, __HIP_MEMORY_SCOPE_AGENT);
    } else {
      while ((unsigned)(__hip_atomic_load(bar, __ATOMIC_ACQUIRE, __HIP_MEMORY_SCOPE_AGENT) >> 32) == g) {
        __builtin_amdgcn_s_sleep(1);
      }
    }
  }
  __syncthreads();
}

__global__ void k_zero(float* ws) {
  *(unsigned long long*)(ws + OFF_BAR) = 0ull;
}

#define FMA4(acc, s, f4)                      \
  acc.x = fmaf((s), (f4).x, acc.x);           \
  acc.y = fmaf((s), (f4).y, acc.y);           \
  acc.z = fmaf((s), (f4).z, acc.z);           \
  acc.w = fmaf((s), (f4).w, acc.w);

// Gauss-Jordan element update (in-place inverse, no pivoting)
#define GJEL(nvc, owc, prc, jj)                                   \
  nvc = ip_ ? (prc) * ipiv : fmaf(-gml, (prc), (owc));            \
  nvc = ((jj) == p) ? (ip_ ? ipiv : -gml) : nvc;

__global__ __launch_bounds__(256) void k_ric(
    const float* __restrict__ A, const float* __restrict__ B,
    const float* __restrict__ W, const float* __restrict__ bphi,
    const float* __restrict__ xg, const float* __restrict__ qlog,
    const float* __restrict__ rlog, float* __restrict__ ws)
{
  const int w = blockIdx.x;
  const int t = threadIdx.x;

  float* V   = ws + OFF_V;
  float* VA  = ws + OFF_VA;
  float* Hm  = ws + OFF_H;
  float* Gm  = ws + OFF_G;
  float* K0  = ws + OFF_K0;
  float* Mm  = ws + OFF_M;
  float* MI  = ws + OFF_MI;
  float* vv  = ws + OFF_v;
  float* Atv = ws + OFF_ATV;
  float* Zv  = ws + OFF_Z;
  float* GG  = ws + OFF_GG;
  float* Qg  = ws + OFF_QG;
  float* Qd  = ws + OFF_QD;
  float* Rd  = ws + OFF_RD;
  float* Kv  = ws + OFF_KV;
  float* NKT = ws + OFF_NKT;
  float* Cv  = ws + OFF_CV;
  unsigned long long* bar = (unsigned long long*)(ws + OFF_BAR);

  __shared__ float sM[64][68];   // GJ workspace / Minv stage (stride 68 -> 16B aligned rows)
  __shared__ float sGc[4][64];
  __shared__ float sKc[4][64];
  __shared__ float sRed[4][64];
  __shared__ float sB[256];      // B column w (constant across iterations)
  __shared__ float sVb[256];
  __shared__ float sVec[256];
  __shared__ float sZ[64];

  // ---------------- init ----------------
  sB[t] = B[t * UD + w];
  for (int rr = 0; rr < 4; ++rr) {
    int r = 4 * w + rr;
    V[r * KD + t] = (r == t) ? expf(qlog[r]) : 0.f;
  }
  if (w < 4 && t < 64) {
    int i = w * 64 + t;
    float acc = 0.f;
    for (int p = 0; p < XD; ++p) acc = fmaf(W[i * XD + p], xg[p], acc);
    float g = acc + bphi[i];
    float qd = expf(qlog[i]);
    GG[i] = g; Qd[i] = qd; Qg[i] = qd * g; vv[i] = qd * g;
  }
  if (w == 4 && t < UD) Rd[t] = expf(rlog[t]);
  gbar(bar);

  const int rb  = (w >> 3) * 32, cb = (w & 7) * 32;
  const int tr  = t >> 3;          // 0..31
  const int tc4 = (t & 7) * 4;     // 0..28

  auto h_tile = [&](int u) {
    const int rbH = (u >> 3) * 32, cbH = (u & 7) * 32;
    const int r = rbH + tr;
    float4 acc = {0.f, 0.f, 0.f, 0.f};
#pragma unroll 4
    for (int p = 0; p < KD; ++p) {
      float av = A[p * KD + r];
      float4 f4 = *(const float4*)(VA + p * KD + cbH + tc4);
      FMA4(acc, av, f4)
    }
    *(float4*)(Hm + r * KD + cbH + tc4) = acc;
  };
  auto g_blk = [&](int u) {
    const int jb = (u - 64) * 16;
    const int j = t >> 2, c4 = jb + (t & 3) * 4;
    float4 acc = {0.f, 0.f, 0.f, 0.f};
#pragma unroll 4
    for (int p = 0; p < KD; ++p) {
      float bv = B[p * UD + j];
      float4 f4 = *(const float4*)(VA + p * KD + c4);
      FMA4(acc, bv, f4)
    }
    *(float4*)(Gm + j * KD + c4) = acc;
  };

  const int c0 = 4 * w;

  for (int it = 0; it < TH; ++it) {
    // ---------- P1: VA tile + M column w ----------
    {
      const float* Vr = V + (rb + tr) * KD;
      float4 acc = {0.f, 0.f, 0.f, 0.f};
#pragma unroll 4
      for (int p = 0; p < KD; ++p) {
        float vs = Vr[p];
        float4 a4 = *(const float4*)(A + p * KD + cb + tc4);
        FMA4(acc, vs, a4)
      }
      *(float4*)(VA + (rb + tr) * KD + cb + tc4) = acc;
    }
    {
      // VBcol[p] = (V B[:,w])[p] computed via symmetry: sum_q V[q][t] * B[q][w]
      float acc = 0.f;
#pragma unroll 4
      for (int q = 0; q < KD; ++q) acc = fmaf(V[q * KD + t], sB[q], acc);
      sVb[t] = acc;
    }
    __syncthreads();
    {
      int i = t & 63, part = t >> 6;
      float acc = 0.f;
      const float* Bp = B + (part * 64) * UD + i;
      const float* vb = sVb + part * 64;
#pragma unroll 4
      for (int p = 0; p < 64; ++p) acc = fmaf(Bp[p * UD], vb[p], acc);
      sRed[part][i] = acc;
    }
    __syncthreads();
    if (t < 64) {
      float m = sRed[0][t] + sRed[1][t] + sRed[2][t] + sRed[3][t];
      if (t == w) m += Rd[w];
      Mm[w * UD + t] = m;
    }
    gbar(bar);

    // ---------- P2: WG0 inverts M; others compute H = At*VA, G = Bt*VA ----------
    if (w == 0) {
      {
        int i = t & 63, cg = t >> 6;
#pragma unroll
        for (int m = 0; m < 4; ++m)
          *(float4*)&sM[i][cg * 16 + 4 * m] = *(const float4*)(Mm + i * UD + cg * 16 + 4 * m);
      }
      __syncthreads();
      {
        const int i = t & 63, cg = t >> 6, base = cg * 16;
#pragma unroll 1
        for (int p = 0; p < 64; ++p) {
          float ipiv = 1.0f / sM[p][p];
          float f = sM[i][p];
          float4 pr0 = *(float4*)&sM[p][base + 0];
          float4 pr1 = *(float4*)&sM[p][base + 4];
          float4 pr2 = *(float4*)&sM[p][base + 8];
          float4 pr3 = *(float4*)&sM[p][base + 12];
          float4 ow0 = *(float4*)&sM[i][base + 0];
          float4 ow1 = *(float4*)&sM[i][base + 4];
          float4 ow2 = *(float4*)&sM[i][base + 8];
          float4 ow3 = *(float4*)&sM[i][base + 12];
          __syncthreads();
          const bool ip_ = (i == p);
          const float gml = f * ipiv;
          float4 nv0, nv1, nv2, nv3;
          GJEL(nv0.x, ow0.x, pr0.x, base + 0)  GJEL(nv0.y, ow0.y, pr0.y, base + 1)
          GJEL(nv0.z, ow0.z, pr0.z, base + 2)  GJEL(nv0.w, ow0.w, pr0.w, base + 3)
          GJEL(nv1.x, ow1.x, pr1.x, base + 4)  GJEL(nv1.y, ow1.y, pr1.y, base + 5)
          GJEL(nv1.z, ow1.z, pr1.z, base + 6)  GJEL(nv1.w, ow1.w, pr1.w, base + 7)
          GJEL(nv2.x, ow2.x, pr2.x, base + 8)  GJEL(nv2.y, ow2.y, pr2.y, base + 9)
          GJEL(nv2.z, ow2.z, pr2.z, base + 10) GJEL(nv2.w, ow2.w, pr2.w, base + 11)
          GJEL(nv3.x, ow3.x, pr3.x, base + 12) GJEL(nv3.y, ow3.y, pr3.y, base + 13)
          GJEL(nv3.z, ow3.z, pr3.z, base + 14) GJEL(nv3.w, ow3.w, pr3.w, base + 15)
          *(float4*)&sM[i][base + 0]  = nv0;
          *(float4*)&sM[i][base + 4]  = nv1;
          *(float4*)&sM[i][base + 8]  = nv2;
          *(float4*)&sM[i][base + 12] = nv3;
          __syncthreads();
        }
      }
      {
        int i = t & 63, cg = t >> 6;
#pragma unroll
        for (int m = 0; m < 4; ++m)
          *(float4*)(MI + i * UD + cg * 16 + 4 * m) = *(float4*)&sM[i][cg * 16 + 4 * m];
      }
    } else {
      if (w == 1 || w == 2) sVec[t] = vv[t];
      __syncthreads();
      h_tile(w - 1);                       // H tiles 0..62
      if (w <= 17) {
        int u = w + 62;                    // 63..79
        if (u < 64) h_tile(u); else g_blk(u);
      }
      if (w == 1) {                        // Atv = At @ v
        float acc = 0.f;
#pragma unroll 4
        for (int p = 0; p < KD; ++p) acc = fmaf(A[p * KD + t], sVec[p], acc);
        Atv[t] = acc;
      }
      if (w == 2 && t < UD) {              // z = Bt @ v
        float acc = 0.f;
#pragma unroll 4
        for (int p = 0; p < KD; ++p) acc = fmaf(B[p * UD + t], sVec[p], acc);
        Zv[t] = acc;
      }
    }
    gbar(bar);

    // ---------- P3: K cols, V' cols, v' ----------
    {
      int i = t & 63, cg = t >> 6;
#pragma unroll
      for (int m = 0; m < 4; ++m)
        *(float4*)&sM[i][cg * 16 + 4 * m] = *(const float4*)(MI + i * UD + cg * 16 + 4 * m);
    }
    if (t < 64) {
      float4 gq = *(const float4*)(Gm + t * KD + c0);
      sGc[0][t] = gq.x; sGc[1][t] = gq.y; sGc[2][t] = gq.z; sGc[3][t] = gq.w;
      sZ[t] = Zv[t];
    }
    __syncthreads();
    {
      int i = t & 63, cc = t >> 6;
      float acc = 0.f;
#pragma unroll 4
      for (int m = 0; m < 64; ++m) acc = fmaf(sM[i][m], sGc[cc][m], acc);
      sKc[cc][i] = acc;
    }
    __syncthreads();
    {
      const int lane = t & 63, cc = t >> 6, c = c0 + cc;
      float a0 = 0.f, a1 = 0.f, a2 = 0.f, a3 = 0.f;
#pragma unroll 4
      for (int m = 0; m < 64; ++m) {
        float kmc = sKc[cc][m];
        const float* Gr = Gm + m * KD + lane;
        a0 = fmaf(Gr[0],   kmc, a0);
        a1 = fmaf(Gr[64],  kmc, a1);
        a2 = fmaf(Gr[128], kmc, a2);
        a3 = fmaf(Gr[192], kmc, a3);
      }
      int r = lane;
      V[c * KD + r] = Hm[c * KD + r] - a0 + ((r == c) ? Qd[r] : 0.f);
      r = lane + 64;
      V[c * KD + r] = Hm[c * KD + r] - a1 + ((r == c) ? Qd[r] : 0.f);
      r = lane + 128;
      V[c * KD + r] = Hm[c * KD + r] - a2 + ((r == c) ? Qd[r] : 0.f);
      r = lane + 192;
      V[c * KD + r] = Hm[c * KD + r] - a3 + ((r == c) ? Qd[r] : 0.f);
    }
    if (t < 4) {
      int c = c0 + t;
      float acc = 0.f;
#pragma unroll 4
      for (int m = 0; m < UD; ++m) acc = fmaf(sKc[t][m], sZ[m], acc);
      vv[c] = Atv[c] - acc + Qg[c];
    }
    if (it == TH - 1) {
      int i = t & 63, cc = t >> 6;
      K0[i * KD + c0 + cc] = sKc[cc][i];
      if (w == 0 && t < 64) {
        float acc = 0.f;
#pragma unroll 4
        for (int m = 0; m < UD; ++m) acc = fmaf(sM[t][m], sZ[m], acc);
        Kv[t] = acc;
      }
    }
    gbar(bar);
  }

  // ---------- final: negKeffT = -(K0 @ W)^T, cvec = kv - K0 @ b ----------
  if (t < 128) {
    int j = t & 63, kk = 2 * w + (t >> 6);
    float acc = 0.f;
#pragma unroll 4
    for (int i = 0; i < KD; ++i) acc = fmaf(K0[j * KD + i], W[i * XD + kk], acc);
    NKT[kk * UD + j] = -acc;
  }
  if (w == 32 && t < UD) {
    float acc = 0.f;
#pragma unroll 4
    for (int i = 0; i < KD; ++i) acc = fmaf(K0[t * KD + i], bphi[i], acc);
    Cv[t] = Kv[t] - acc;
  }
}

__global__ __launch_bounds__(256) void k_batch(const float* __restrict__ x0,
                                               const float* __restrict__ ws,
                                               float* __restrict__ out)
{
  __shared__ float kt[XD][UD];   // 32 KB: negKeffT
  __shared__ float cvs[UD];
  const int t = threadIdx.x;
  {
    const float4* src = (const float4*)(ws + OFF_NKT);
    float4* dst = (float4*)kt;
#pragma unroll
    for (int idx = 0; idx < (XD * UD / 4) / 256; ++idx)
      dst[t + idx * 256] = src[t + idx * 256];
  }
  if (t < UD) cvs[t] = ws[OFF_CV + t];
  __syncthreads();

  const int ty = t >> 4, tx = t & 15;
  const long r0 = (long)blockIdx.x * 64 + ty * 4;
  const float* xp = x0 + r0 * XD;

  float4 acc0 = {0,0,0,0}, acc1 = {0,0,0,0}, acc2 = {0,0,0,0}, acc3 = {0,0,0,0};
#pragma unroll 2
  for (int k = 0; k < XD; k += 4) {
    float4 x_0 = *(const float4*)(xp + 0 * XD + k);
    float4 x_1 = *(const float4*)(xp + 1 * XD + k);
    float4 x_2 = *(const float4*)(xp + 2 * XD + k);
    float4 x_3 = *(const float4*)(xp + 3 * XD + k);
    float4 k_0 = *(const float4*)&kt[k + 0][tx * 4];
    float4 k_1 = *(const float4*)&kt[k + 1][tx * 4];
    float4 k_2 = *(const float4*)&kt[k + 2][tx * 4];
    float4 k_3 = *(const float4*)&kt[k + 3][tx * 4];
    FMA4(acc0, x_0.x, k_0) FMA4(acc0, x_0.y, k_1) FMA4(acc0, x_0.z, k_2) FMA4(acc0, x_0.w, k_3)
    FMA4(acc1, x_1.x, k_0) FMA4(acc1, x_1.y, k_1) FMA4(acc1, x_1.z, k_2) FMA4(acc1, x_1.w, k_3)
    FMA4(acc2, x_2.x, k_0) FMA4(acc2, x_2.y, k_1) FMA4(acc2, x_2.z, k_2) FMA4(acc2, x_2.w, k_3)
    FMA4(acc3, x_3.x, k_0) FMA4(acc3, x_3.y, k_1) FMA4(acc3, x_3.z, k_2) FMA4(acc3, x_3.w, k_3)
  }
  float4 cq = *(float4*)&cvs[tx * 4];
  acc0.x += cq.x; acc0.y += cq.y; acc0.z += cq.z; acc0.w += cq.w;
  acc1.x += cq.x; acc1.y += cq.y; acc1.z += cq.z; acc1.w += cq.w;
  acc2.x += cq.x; acc2.y += cq.y; acc2.z += cq.z; acc2.w += cq.w;
  acc3.x += cq.x; acc3.y += cq.y; acc3.z += cq.z; acc3.w += cq.w;
  *(float4*)(out + (r0 + 0) * UD + tx * 4) = acc0;
  *(float4*)(out + (r0 + 1) * UD + tx * 4) = acc1;
  *(float4*)(out + (r0 + 2) * UD + tx * 4) = acc2;
  *(float4*)(out + (r0 + 3) * UD + tx * 4) = acc3;
}

extern "C" void kernel_launch(void* const* d_in, const int* in_sizes, int n_in,
                              void* d_out, int out_size, void* d_ws, size_t ws_size,
                              hipStream_t stream) {
  const float* x0   = (const float*)d_in[0];
  const float* W    = (const float*)d_in[1];
  const float* bphi = (const float*)d_in[2];
  const float* xg   = (const float*)d_in[3];
  const float* A    = (const float*)d_in[4];
  const float* B    = (const float*)d_in[5];
  const float* ql   = (const float*)d_in[6];
  const float* rl   = (const float*)d_in[7];
  float* ws  = (float*)d_ws;
  float* out = (float*)d_out;

  hipLaunchKernelGGL(k_zero, dim3(1), dim3(1), 0, stream, ws);
  hipLaunchKernelGGL(k_ric, dim3(NWG), dim3(256), 0, stream,
                     A, B, W, bphi, xg, ql, rl, ws);
  int rows = in_sizes[0] / XD;
  int nblk = rows / 64;
  hipLaunchKernelGGL(k_batch, dim3(nblk), dim3(256), 0, stream, x0, ws, out);
}

// Round 2
// 16304.875 us; speedup vs baseline: 1.5861x; 1.5861x over previous
//
#include <hip/hip_runtime.h>
#include <math.h>

#define NWG 65
#define KD 256
#define UD 64
#define XD 128
#define TH 200

// ws float offsets
#define OFF_V     0
#define OFF_WA    65536
#define OFF_H     131072
#define OFF_G     196608
#define OFF_VB    212992
#define OFF_K0    229376
#define OFF_MI    245760
#define OFF_v     249856
#define OFF_ATV   250112
#define OFF_Z     250368
#define OFF_QG    250432
#define OFF_QD    250688
#define OFF_RD    250944
#define OFF_KV    251008
#define OFF_CV    251072
#define OFF_NKT   251136
#define OFF_FLAGS 259328   // unsigned[65*16], padded one flag per 64B

#define FMA4(acc, s, f4)                      \
  acc.x = fmaf((s), (f4).x, acc.x);           \
  acc.y = fmaf((s), (f4).y, acc.y);           \
  acc.z = fmaf((s), (f4).z, acc.z);           \
  acc.w = fmaf((s), (f4).w, acc.w);

// Gauss-Jordan element update (in-place inverse, no pivoting; M SPD, well-conditioned)
#define GJEL(nvc, owc, prc, jj)                                   \
  nvc = ip_ ? (prc) * ipiv : fmaf(-gml, (prc), (owc));            \
  nvc = ((jj) == p) ? (ip_ ? ipiv : -gml) : nvc;

// Contention-free grid barrier: each WG release-stores its own padded flag,
// then 65 lanes poll the 65 flags in parallel (acquire). No RMW serialization.
__device__ __forceinline__ void gbar(unsigned* flags, unsigned ep) {
  __syncthreads();
  const int t = threadIdx.x;
  if (t == 0)
    __hip_atomic_store(&flags[blockIdx.x * 16], ep, __ATOMIC_RELEASE, __HIP_MEMORY_SCOPE_AGENT);
  if (t < NWG) {
    while (__hip_atomic_load(&flags[t * 16], __ATOMIC_ACQUIRE, __HIP_MEMORY_SCOPE_AGENT) < ep)
      __builtin_amdgcn_s_sleep(1);
  }
  __syncthreads();
}

__global__ void k_zero(float* ws) {
  unsigned* f = (unsigned*)(ws + OFF_FLAGS);
  for (int i = threadIdx.x; i < 1088; i += 256) f[i] = 0u;
}

__global__ __launch_bounds__(256) void k_ric(
    const float* __restrict__ A, const float* __restrict__ B,
    const float* __restrict__ W, const float* __restrict__ bphi,
    const float* __restrict__ xg, const float* __restrict__ qlog,
    const float* __restrict__ rlog, float* __restrict__ ws)
{
  const int w = blockIdx.x;
  const int t = threadIdx.x;
  const int u = w - 1;          // worker index 0..63 (w>=1); WG0 = inverter

  float* V   = ws + OFF_V;
  float* WA  = ws + OFF_WA;
  float* Hm  = ws + OFF_H;
  float* Gm  = ws + OFF_G;
  float* VB  = ws + OFF_VB;
  float* K0  = ws + OFF_K0;
  float* MI  = ws + OFF_MI;
  float* vv  = ws + OFF_v;
  float* Atv = ws + OFF_ATV;
  float* Zv  = ws + OFF_Z;
  float* Qg  = ws + OFF_QG;
  float* Qd  = ws + OFF_QD;
  float* Rd  = ws + OFF_RD;
  float* Kv  = ws + OFF_KV;
  float* Cv  = ws + OFF_CV;
  float* NKT = ws + OFF_NKT;
  unsigned* flags = (unsigned*)(ws + OFF_FLAGS);

  // LDS map (floats): sA[256][32] A-strip (or WG0 staging), sBsl[256][8] B-slice,
  // sM [64][68] GJ workspace (WG0) / [64][65] MI copy (workers), sG/sK[4][64], sZ[64]
  __shared__ float smem[15168];
  float* sA   = smem;            // 8192
  float* sBsl = smem + 8192;     // 2048
  float* sM   = smem + 10240;    // 4352
  float* sG   = smem + 14592;    // 256
  float* sK   = smem + 14848;    // 256
  float* sZ   = smem + 15104;    // 64

  unsigned ep = 0;
  const int tr  = t >> 3;        // 0..31
  const int tc4 = (t & 7) * 4;   // 0..28
  const int cb0 = (u & 7) * 32;  // worker's A column strip / H row block
  const int m0  = (u & 7) * 8;   // worker's B column slice (G rows)

  // ---------------- init ----------------
  if (w < 64) {
    for (int rr = 0; rr < 4; ++rr) {
      int r = 4 * w + rr;
      V[r * KD + t] = (r == t) ? expf(qlog[r]) : 0.f;
    }
  }
  if (w < 4 && t < 64) {
    int i = w * 64 + t;
    float acc = 0.f;
    for (int p = 0; p < XD; ++p) acc = fmaf(W[i * XD + p], xg[p], acc);
    float g = acc + bphi[i];
    float qd = expf(qlog[i]);
    Qd[i] = qd; Qg[i] = qd * g; vv[i] = qd * g;
  }
  if (w == 4 && t < UD) Rd[t] = expf(rlog[t]);
  if (w >= 1) {
    for (int i = 0; i < 32; ++i) { int idx = i * 256 + t; sA[idx]   = A[(idx >> 5) * KD + cb0 + (idx & 31)]; }
    for (int i = 0; i < 8;  ++i) { int idx = i * 256 + t; sBsl[idx] = B[(idx >> 3) * UD + m0 + (idx & 7)]; }
  }
  gbar(flags, ++ep);

  for (int it = 0; it < TH; ++it) {
    // ---------- PhA: WA tiles, VB slices, Atv, z ----------
    if (w >= 1) {
      const int rb = (u >> 3) * 32;
      {
        const float* Vr = V + (rb + tr) * KD;
        float4 acc = {0.f, 0.f, 0.f, 0.f};
#pragma unroll 4
        for (int p = 0; p < KD; ++p) {
          float vs = Vr[p];
          float4 a4 = *(const float4*)&sA[p * 32 + tc4];
          FMA4(acc, vs, a4)
        }
        *(float4*)(WA + (rb + tr) * KD + cb0 + tc4) = acc;
      }
      {
        const int r4 = t >> 6, m = t & 63;
        const float* Vr2 = V + (4 * u + r4) * KD;
        float acc = 0.f;
#pragma unroll 4
        for (int p = 0; p < KD; ++p) acc = fmaf(Vr2[p], B[p * UD + m], acc);
        VB[(4 * u + r4) * UD + m] = acc;
      }
      if (u < 8 && t < 32) {
        float acc = 0.f;
#pragma unroll 4
        for (int p = 0; p < KD; ++p) acc = fmaf(sA[p * 32 + t], vv[p], acc);
        Atv[u * 32 + t] = acc;
      }
      if (u >= 8 && u < 16 && t < 8) {
        float acc = 0.f;
#pragma unroll 4
        for (int p = 0; p < KD; ++p) acc = fmaf(sBsl[p * 8 + t], vv[p], acc);
        Zv[(u - 8) * 8 + t] = acc;
      }
    }
    gbar(flags, ++ep);

    // ---------- PhB: WG0 assembles M = Bt@VB + R and inverts; workers: H tiles + G slices ----------
    if (w == 0) {
      const int a = t >> 2, b0 = (t & 3) * 16;
      float macc[16];
#pragma unroll
      for (int i = 0; i < 16; ++i) macc[i] = 0.f;
      for (int ch = 0; ch < 4; ++ch) {
        const int p0 = ch * 64;
        for (int i = 0; i < 16; ++i) { int idx = i * 256 + t; sA[idx]        = B [(p0 + (idx >> 6)) * UD + (idx & 63)]; }
        for (int i = 0; i < 16; ++i) { int idx = i * 256 + t; sA[4096 + idx] = VB[(p0 + (idx >> 6)) * UD + (idx & 63)]; }
        __syncthreads();
#pragma unroll 4
        for (int pp = 0; pp < 64; ++pp) {
          float bv = sA[pp * 64 + a];
          const float* vr = &sA[4096 + pp * 64 + b0];
#pragma unroll
          for (int i = 0; i < 16; ++i) macc[i] = fmaf(bv, vr[i], macc[i]);
        }
        __syncthreads();
      }
      if (a >= b0 && a < b0 + 16) macc[a - b0] += Rd[a];
#pragma unroll
      for (int i = 0; i < 16; ++i) sM[a * 68 + b0 + i] = macc[i];
      __syncthreads();
      // Gauss-Jordan in-place inverse of sM (64x64, stride 68)
      {
        const int i = t & 63, cg = t >> 6, base = cg * 16;
#pragma unroll 1
        for (int p = 0; p < 64; ++p) {
          float ipiv = 1.0f / sM[p * 68 + p];
          float f = sM[i * 68 + p];
          float4 pr0 = *(float4*)&sM[p * 68 + base + 0];
          float4 pr1 = *(float4*)&sM[p * 68 + base + 4];
          float4 pr2 = *(float4*)&sM[p * 68 + base + 8];
          float4 pr3 = *(float4*)&sM[p * 68 + base + 12];
          float4 ow0 = *(float4*)&sM[i * 68 + base + 0];
          float4 ow1 = *(float4*)&sM[i * 68 + base + 4];
          float4 ow2 = *(float4*)&sM[i * 68 + base + 8];
          float4 ow3 = *(float4*)&sM[i * 68 + base + 12];
          __syncthreads();
          const bool ip_ = (i == p);
          const float gml = f * ipiv;
          float4 nv0, nv1, nv2, nv3;
          GJEL(nv0.x, ow0.x, pr0.x, base + 0)  GJEL(nv0.y, ow0.y, pr0.y, base + 1)
          GJEL(nv0.z, ow0.z, pr0.z, base + 2)  GJEL(nv0.w, ow0.w, pr0.w, base + 3)
          GJEL(nv1.x, ow1.x, pr1.x, base + 4)  GJEL(nv1.y, ow1.y, pr1.y, base + 5)
          GJEL(nv1.z, ow1.z, pr1.z, base + 6)  GJEL(nv1.w, ow1.w, pr1.w, base + 7)
          GJEL(nv2.x, ow2.x, pr2.x, base + 8)  GJEL(nv2.y, ow2.y, pr2.y, base + 9)
          GJEL(nv2.z, ow2.z, pr2.z, base + 10) GJEL(nv2.w, ow2.w, pr2.w, base + 11)
          GJEL(nv3.x, ow3.x, pr3.x, base + 12) GJEL(nv3.y, ow3.y, pr3.y, base + 13)
          GJEL(nv3.z, ow3.z, pr3.z, base + 14) GJEL(nv3.w, ow3.w, pr3.w, base + 15)
          *(float4*)&sM[i * 68 + base + 0]  = nv0;
          *(float4*)&sM[i * 68 + base + 4]  = nv1;
          *(float4*)&sM[i * 68 + base + 8]  = nv2;
          *(float4*)&sM[i * 68 + base + 12] = nv3;
          __syncthreads();
        }
      }
      {
        int i = t & 63, cg = t >> 6;
#pragma unroll
        for (int mq = 0; mq < 4; ++mq)
          *(float4*)(MI + i * UD + cg * 16 + 4 * mq) = *(float4*)&sM[i * 68 + cg * 16 + 4 * mq];
      }
    } else {
      const int rp = cb0, cp = (u >> 3) * 32;
      {
        float4 acc = {0.f, 0.f, 0.f, 0.f};
#pragma unroll 4
        for (int p = 0; p < KD; ++p) {
          float av = sA[p * 32 + tr];
          float4 w4 = *(const float4*)(WA + p * KD + cp + tc4);
          FMA4(acc, av, w4)
        }
        *(float4*)(Hm + (rp + tr) * KD + cp + tc4) = acc;
      }
      {
        const int mg = t >> 5, cg = cp + (t & 31);
        float acc = 0.f;
#pragma unroll 4
        for (int p = 0; p < KD; ++p) acc = fmaf(sBsl[p * 8 + mg], WA[p * KD + cg], acc);
        Gm[(m0 + mg) * KD + cg] = acc;
      }
    }
    gbar(flags, ++ep);

    // ---------- PhC: K cols, V' cols, v'; WG0: kv on last iter ----------
    if (w >= 1) {
      const int c0 = 4 * u;
      for (int i = 0; i < 16; ++i) {
        int lin = i * 256 + t;
        sM[(lin >> 6) * 65 + (lin & 63)] = MI[lin];
      }
      { int m = t & 63, j = t >> 6; sG[j * 64 + m] = Gm[m * KD + c0 + j]; }
      if (t < 64) sZ[t] = Zv[t];
      __syncthreads();
      {
        int m = t & 63, j = t >> 6;
        float acc = 0.f;
#pragma unroll 4
        for (int p = 0; p < UD; ++p) acc = fmaf(sM[m * 65 + p], sG[j * 64 + p], acc);
        sK[j * 64 + m] = acc;
        if (it == TH - 1) K0[m * KD + c0 + j] = acc;
      }
      __syncthreads();
      {
        const int r = t;
        float4 h4 = *(const float4*)(Hm + r * KD + c0);
        float a0 = 0.f, a1 = 0.f, a2 = 0.f, a3 = 0.f;
#pragma unroll 4
        for (int m = 0; m < UD; ++m) {
          float g = Gm[m * KD + r];
          a0 = fmaf(g, sK[0 * 64 + m], a0);
          a1 = fmaf(g, sK[1 * 64 + m], a1);
          a2 = fmaf(g, sK[2 * 64 + m], a2);
          a3 = fmaf(g, sK[3 * 64 + m], a3);
        }
        float4 v4;
        v4.x = h4.x - a0 + ((r == c0 + 0) ? Qd[r] : 0.f);
        v4.y = h4.y - a1 + ((r == c0 + 1) ? Qd[r] : 0.f);
        v4.z = h4.z - a2 + ((r == c0 + 2) ? Qd[r] : 0.f);
        v4.w = h4.w - a3 + ((r == c0 + 3) ? Qd[r] : 0.f);
        *(float4*)(V + r * KD + c0) = v4;
      }
      if (t < 4) {
        float acc = 0.f;
#pragma unroll 4
        for (int m = 0; m < UD; ++m) acc = fmaf(sK[t * 64 + m], sZ[m], acc);
        vv[c0 + t] = Atv[c0 + t] - acc + Qg[c0 + t];
      }
    } else {
      if (it == TH - 1 && t < 64) {
        float acc = 0.f;
#pragma unroll 4
        for (int p = 0; p < UD; ++p) acc = fmaf(sM[t * 68 + p], Zv[p], acc);
        Kv[t] = acc;
      }
    }
    gbar(flags, ++ep);
  }

  // ---------- final: NKT = -(K0 @ W)^T, Cv = kv - K0 @ b ----------
  if (w >= 1 && t < 128) {
    int j = t & 63, kk = 2 * u + (t >> 6);
    float acc = 0.f;
#pragma unroll 4
    for (int i = 0; i < KD; ++i) acc = fmaf(K0[j * KD + i], W[i * XD + kk], acc);
    NKT[kk * UD + j] = -acc;
  }
  if (w == 0 && t < UD) {
    float acc = 0.f;
#pragma unroll 4
    for (int i = 0; i < KD; ++i) acc = fmaf(K0[t * KD + i], bphi[i], acc);
    Cv[t] = Kv[t] - acc;
  }
}

__global__ __launch_bounds__(256) void k_batch(const float* __restrict__ x0,
                                               const float* __restrict__ ws,
                                               float* __restrict__ out)
{
  __shared__ float kt[XD][UD];   // 32 KB: negKeffT
  __shared__ float cvs[UD];
  const int t = threadIdx.x;
  {
    const float4* src = (const float4*)(ws + OFF_NKT);
    float4* dst = (float4*)kt;
#pragma unroll
    for (int idx = 0; idx < (XD * UD / 4) / 256; ++idx)
      dst[t + idx * 256] = src[t + idx * 256];
  }
  if (t < UD) cvs[t] = ws[OFF_CV + t];
  __syncthreads();

  const int ty = t >> 4, tx = t & 15;
  const long r0 = (long)blockIdx.x * 64 + ty * 4;
  const float* xp = x0 + r0 * XD;

  float4 acc0 = {0,0,0,0}, acc1 = {0,0,0,0}, acc2 = {0,0,0,0}, acc3 = {0,0,0,0};
#pragma unroll 2
  for (int k = 0; k < XD; k += 4) {
    float4 x_0 = *(const float4*)(xp + 0 * XD + k);
    float4 x_1 = *(const float4*)(xp + 1 * XD + k);
    float4 x_2 = *(const float4*)(xp + 2 * XD + k);
    float4 x_3 = *(const float4*)(xp + 3 * XD + k);
    float4 k_0 = *(const float4*)&kt[k + 0][tx * 4];
    float4 k_1 = *(const float4*)&kt[k + 1][tx * 4];
    float4 k_2 = *(const float4*)&kt[k + 2][tx * 4];
    float4 k_3 = *(const float4*)&kt[k + 3][tx * 4];
    FMA4(acc0, x_0.x, k_0) FMA4(acc0, x_0.y, k_1) FMA4(acc0, x_0.z, k_2) FMA4(acc0, x_0.w, k_3)
    FMA4(acc1, x_1.x, k_0) FMA4(acc1, x_1.y, k_1) FMA4(acc1, x_1.z, k_2) FMA4(acc1, x_1.w, k_3)
    FMA4(acc2, x_2.x, k_0) FMA4(acc2, x_2.y, k_1) FMA4(acc2, x_2.z, k_2) FMA4(acc2, x_2.w, k_3)
    FMA4(acc3, x_3.x, k_0) FMA4(acc3, x_3.y, k_1) FMA4(acc3, x_3.z, k_2) FMA4(acc3, x_3.w, k_3)
  }
  float4 cq = *(float4*)&cvs[tx * 4];
  acc0.x += cq.x; acc0.y += cq.y; acc0.z += cq.z; acc0.w += cq.w;
  acc1.x += cq.x; acc1.y += cq.y; acc1.z += cq.z; acc1.w += cq.w;
  acc2.x += cq.x; acc2.y += cq.y; acc2.z += cq.z; acc2.w += cq.w;
  acc3.x += cq.x; acc3.y += cq.y; acc3.z += cq.z; acc3.w += cq.w;
  *(float4*)(out + (r0 + 0) * UD + tx * 4) = acc0;
  *(float4*)(out + (r0 + 1) * UD + tx * 4) = acc1;
  *(float4*)(out + (r0 + 2) * UD + tx * 4) = acc2;
  *(float4*)(out + (r0 + 3) * UD + tx * 4) = acc3;
}

extern "C" void kernel_launch(void* const* d_in, const int* in_sizes, int n_in,
                              void* d_out, int out_size, void* d_ws, size_t ws_size,
                              hipStream_t stream) {
  const float* x0   = (const float*)d_in[0];
  const float* W    = (const float*)d_in[1];
  const float* bphi = (const float*)d_in[2];
  const float* xg   = (const float*)d_in[3];
  const float* A    = (const float*)d_in[4];
  const float* B    = (const float*)d_in[5];
  const float* ql   = (const float*)d_in[6];
  const float* rl   = (const float*)d_in[7];
  float* ws  = (float*)d_ws;
  float* out = (float*)d_out;

  hipLaunchKernelGGL(k_zero, dim3(1), dim3(256), 0, stream, ws);
  hipLaunchKernelGGL(k_ric, dim3(NWG), dim3(256), 0, stream,
                     A, B, W, bphi, xg, ql, rl, ws);
  int rows = in_sizes[0] / XD;
  int nblk = rows / 64;
  hipLaunchKernelGGL(k_batch, dim3(nblk), dim3(256), 0, stream, x0, ws, out);
}